// Round 1
// baseline (1332.255 us; speedup 1.0000x reference)
//
#include <hip/hip_runtime.h>
#include <stdint.h>

// VisionBlock: LN1 -> QKV GEMM -> RoPE -> windowed attn (W=64) -> proj+res -> LN2 -> GELU MLP + res
// All heavy GEMMs in bf16 MFMA (16x16x32), fp32 accumulate. m97-style 128x128 tile, global_load_lds.

#define SEQ   16384
#define HID   1152
#define NH    16
#define HDIM  72
#define INTER 4304
#define INTERP 4352
#define QKVN  3456

using bf16x8 = __attribute__((ext_vector_type(8))) __bf16;
using f32x4  = __attribute__((ext_vector_type(4))) float;

__device__ __forceinline__ float bf2f(uint16_t u){ return __uint_as_float(((uint32_t)u)<<16); }
__device__ __forceinline__ uint16_t f2bf(float f){
  uint32_t u = __float_as_uint(f);
  u += 0x7fffu + ((u>>16)&1u);
  return (uint16_t)(u>>16);
}
__device__ __forceinline__ float gelu_tanh(float x){
  float t = tanhf(0.7978845608028654f*(x + 0.044715f*x*x*x));
  return 0.5f*x*(1.0f + t);
}
__device__ __forceinline__ void async_load16(const void* g, void* l){
  __builtin_amdgcn_global_load_lds((__attribute__((address_space(1))) void*)(void*)g,
                                   (__attribute__((address_space(3))) void*)l, 16, 0, 0);
}

// ---------------- transpose + cast fp32[R][C] -> bf16[Cp][Rp], zero-padded ----------------
__global__ void transpose_cast(const float* __restrict__ src, uint16_t* __restrict__ dst,
                               int R, int C, int Rp)
{
  __shared__ float tile[32][33];
  const int tx = threadIdx.x & 31, ty = threadIdx.x >> 5;
  const int c = blockIdx.x*32 + tx;
  #pragma unroll
  for (int s = 0; s < 4; ++s){
    const int r = blockIdx.y*32 + ty + s*8;
    tile[ty + s*8][tx] = (r < R && c < C) ? src[(size_t)r*C + c] : 0.0f;
  }
  __syncthreads();
  #pragma unroll
  for (int s = 0; s < 4; ++s){
    const int oc = blockIdx.x*32 + ty + s*8;     // output row  (N dim)
    const int orr = blockIdx.y*32 + tx;          // output col  (K dim)
    dst[(size_t)oc*Rp + orr] = f2bf(tile[tx][ty + s*8]);
  }
}

// ---------------- LayerNorm: fp32 in -> bf16 out, one wave per row ----------------
__global__ void ln_kernel(const float* __restrict__ x, const float* __restrict__ w,
                          const float* __restrict__ b, uint16_t* __restrict__ out)
{
  const int wid = threadIdx.x >> 6, lane = threadIdx.x & 63;
  const int row = blockIdx.x*4 + wid;
  const float* xr = x + (size_t)row*HID;
  float v[18];
  float s = 0.f;
  #pragma unroll
  for (int t = 0; t < 18; ++t){ v[t] = xr[lane + t*64]; s += v[t]; }
  #pragma unroll
  for (int m = 32; m; m >>= 1) s += __shfl_xor(s, m, 64);
  const float mean = s * (1.0f/HID);
  float q = 0.f;
  #pragma unroll
  for (int t = 0; t < 18; ++t){ float d = v[t]-mean; q += d*d; }
  #pragma unroll
  for (int m = 32; m; m >>= 1) q += __shfl_xor(q, m, 64);
  const float rstd = rsqrtf(q*(1.0f/HID) + 1e-6f);
  uint16_t* orow = out + (size_t)row*HID;
  #pragma unroll
  for (int t = 0; t < 18; ++t){
    const int j = lane + t*64;
    orow[j] = f2bf((v[t]-mean)*rstd*w[j] + b[j]);
  }
}

// ---------------- RoPE in-place on bf16 qkv [SEQ][3456] (q,k only) ----------------
__global__ void rope_kernel(uint16_t* __restrict__ qkv, const float* __restrict__ cosb,
                            const float* __restrict__ sinb)
{
  const int idx = blockIdx.x*256 + threadIdx.x;      // SEQ*NH*36 threads exactly
  const int s  = idx / (NH*36);
  const int r1 = idx - s*(NH*36);
  const int h  = r1 / 36;
  const int d  = r1 - h*36;
  const float c  = cosb[s*HDIM + d];
  const float sn = sinb[s*HDIM + d];
  const size_t b = (size_t)s*QKVN + h*HDIM + d;
  float q1 = bf2f(qkv[b]), q2 = bf2f(qkv[b+36]);
  qkv[b]    = f2bf(q1*c - q2*sn);
  qkv[b+36] = f2bf(q2*c + q1*sn);
  float k1 = bf2f(qkv[b+HID]), k2 = bf2f(qkv[b+HID+36]);
  qkv[b+HID]    = f2bf(k1*c - k2*sn);
  qkv[b+HID+36] = f2bf(k2*c + k1*sn);
}

// ---------------- windowed attention: one block per (window, head) ----------------
__global__ __launch_bounds__(256,2) void attn_kernel(const uint16_t* __restrict__ qkv,
                                                     uint16_t* __restrict__ outb)
{
  __shared__ float Q[64*76];
  __shared__ float K[64*76];
  __shared__ float V[64*76];
  __shared__ float P[64*68];
  const int tid = threadIdx.x;
  const int win = blockIdx.x >> 4, h = blockIdx.x & 15;
  const size_t base = (size_t)win*64*QKVN + h*HDIM;
  {
    const int r = tid >> 2, q4 = tid & 3;
    const size_t rb = base + (size_t)r*QKVN;
    #pragma unroll
    for (int p0 = 0; p0 < 9; ++p0){
      const int p = q4*9 + p0;
      const uint32_t uq = *(const uint32_t*)(qkv + rb + 2*p);
      const uint32_t uk = *(const uint32_t*)(qkv + rb + HID + 2*p);
      const uint32_t uv = *(const uint32_t*)(qkv + rb + 2*HID + 2*p);
      Q[r*76+2*p] = bf2f((uint16_t)uq); Q[r*76+2*p+1] = bf2f((uint16_t)(uq>>16));
      K[r*76+2*p] = bf2f((uint16_t)uk); K[r*76+2*p+1] = bf2f((uint16_t)(uk>>16));
      V[r*76+2*p] = bf2f((uint16_t)uv); V[r*76+2*p+1] = bf2f((uint16_t)(uv>>16));
    }
  }
  __syncthreads();
  const int rg = tid >> 4, cg = tid & 15;
  const int r0 = rg*4, c0 = cg*4;
  float sc[4][4] = {};
  #pragma unroll 3
  for (int kk = 0; kk < 18; ++kk){
    float4 qv[4], kv[4];
    #pragma unroll
    for (int i = 0; i < 4; ++i) qv[i] = *(const float4*)&Q[(r0+i)*76 + kk*4];
    #pragma unroll
    for (int j = 0; j < 4; ++j) kv[j] = *(const float4*)&K[(c0+j)*76 + kk*4];
    #pragma unroll
    for (int i = 0; i < 4; ++i)
      #pragma unroll
      for (int j = 0; j < 4; ++j)
        sc[i][j] += qv[i].x*kv[j].x + qv[i].y*kv[j].y + qv[i].z*kv[j].z + qv[i].w*kv[j].w;
  }
  const float scale = 0.11785113019775793f;   // 72^-0.5
  #pragma unroll
  for (int i = 0; i < 4; ++i){
    float a0 = sc[i][0]*scale, a1 = sc[i][1]*scale, a2 = sc[i][2]*scale, a3 = sc[i][3]*scale;
    float m = fmaxf(fmaxf(a0,a1), fmaxf(a2,a3));
    m = fmaxf(m, __shfl_xor(m, 1, 16));
    m = fmaxf(m, __shfl_xor(m, 2, 16));
    m = fmaxf(m, __shfl_xor(m, 4, 16));
    m = fmaxf(m, __shfl_xor(m, 8, 16));
    float e0 = __expf(a0-m), e1 = __expf(a1-m), e2 = __expf(a2-m), e3 = __expf(a3-m);
    float sm = e0+e1+e2+e3;
    sm += __shfl_xor(sm, 1, 16);
    sm += __shfl_xor(sm, 2, 16);
    sm += __shfl_xor(sm, 4, 16);
    sm += __shfl_xor(sm, 8, 16);
    const float inv = 1.0f/sm;
    *(float4*)&P[(r0+i)*68 + c0] = make_float4(e0*inv, e1*inv, e2*inv, e3*inv);
  }
  __syncthreads();
  for (int d4 = cg; d4 < 18; d4 += 16){
    float4 o[4] = {};
    #pragma unroll 4
    for (int k4 = 0; k4 < 16; ++k4){
      float4 pr[4];
      #pragma unroll
      for (int i = 0; i < 4; ++i) pr[i] = *(const float4*)&P[(r0+i)*68 + k4*4];
      const float4 v0 = *(const float4*)&V[(k4*4+0)*76 + d4*4];
      const float4 v1 = *(const float4*)&V[(k4*4+1)*76 + d4*4];
      const float4 v2 = *(const float4*)&V[(k4*4+2)*76 + d4*4];
      const float4 v3 = *(const float4*)&V[(k4*4+3)*76 + d4*4];
      #pragma unroll
      for (int i = 0; i < 4; ++i){
        o[i].x += pr[i].x*v0.x + pr[i].y*v1.x + pr[i].z*v2.x + pr[i].w*v3.x;
        o[i].y += pr[i].x*v0.y + pr[i].y*v1.y + pr[i].z*v2.y + pr[i].w*v3.y;
        o[i].z += pr[i].x*v0.z + pr[i].y*v1.z + pr[i].z*v2.z + pr[i].w*v3.z;
        o[i].w += pr[i].x*v0.w + pr[i].y*v1.w + pr[i].z*v2.w + pr[i].w*v3.w;
      }
    }
    #pragma unroll
    for (int i = 0; i < 4; ++i){
      const int token = win*64 + r0 + i;
      const size_t ob = (size_t)token*HID + h*HDIM + d4*4;
      outb[ob+0] = f2bf(o[i].x); outb[ob+1] = f2bf(o[i].y);
      outb[ob+2] = f2bf(o[i].z); outb[ob+3] = f2bf(o[i].w);
    }
  }
}

// ---------------- bf16 GEMM: C[M][N] = A[M][K] @ Bt[N][K]^T, m97-style ----------------
// EPI: 0 = bf16(bias), 1 = bf16(gelu(bias)), 2 = f32(bias + residual)
template<int EPI>
__global__ __launch_bounds__(256,2) void gemm_bt(
    const uint16_t* __restrict__ A, const uint16_t* __restrict__ Bt,
    const float* __restrict__ bias, int Nb,
    const float* res, void* outp, int N, int K)
{
  __shared__ uint16_t sA[128*32];
  __shared__ uint16_t sB[128*32];
  const int tid = threadIdx.x, wid = tid >> 6, lane = tid & 63;
  const int mBase = blockIdx.y*128, nBase = blockIdx.x*128;
  const int wm = wid >> 1, wn = wid & 1;
  const int ar0 = lane >> 2;           // row within 16-row chunk
  const int ac0 = (lane & 3)*8;        // bf16 col offset within 32-wide tile
  f32x4 acc[4][4] = {};

  for (int k0 = 0; k0 < K; k0 += 32){
    __syncthreads();
    #pragma unroll
    for (int cc = 0; cc < 2; ++cc){
      const int c = wid*2 + cc;
      async_load16(A  + (size_t)(mBase + c*16 + ar0)*K + (k0 + ac0), &sA[c*512]);
      async_load16(Bt + (size_t)(nBase + c*16 + ar0)*K + (k0 + ac0), &sB[c*512]);
    }
    __syncthreads();
    bf16x8 af[4], bfr[4];
    #pragma unroll
    for (int i = 0; i < 4; ++i)
      af[i] = *(const bf16x8*)&sA[(wm*64 + i*16 + (lane&15))*32 + (lane>>4)*8];
    #pragma unroll
    for (int j = 0; j < 4; ++j)
      bfr[j] = *(const bf16x8*)&sB[(wn*64 + j*16 + (lane&15))*32 + (lane>>4)*8];
    #pragma unroll
    for (int i = 0; i < 4; ++i)
      #pragma unroll
      for (int j = 0; j < 4; ++j)
        acc[i][j] = __builtin_amdgcn_mfma_f32_16x16x32_bf16(af[i], bfr[j], acc[i][j], 0, 0, 0);
  }

  const int rq = (lane>>4)*4, cl = lane & 15;
  #pragma unroll
  for (int i = 0; i < 4; ++i){
    #pragma unroll
    for (int j = 0; j < 4; ++j){
      const int col = nBase + wn*64 + j*16 + cl;
      const float bv = (col < Nb) ? bias[col] : 0.0f;
      #pragma unroll
      for (int r = 0; r < 4; ++r){
        const int row = mBase + wm*64 + i*16 + rq + r;
        const float v = acc[i][j][r] + bv;
        const size_t o = (size_t)row*N + col;
        if (EPI == 0)      ((uint16_t*)outp)[o] = f2bf(v);
        else if (EPI == 1) ((uint16_t*)outp)[o] = f2bf(gelu_tanh(v));
        else               ((float*)outp)[o] = v + res[o];
      }
    }
  }
}

// ---------------- host launcher ----------------
extern "C" void kernel_launch(void* const* d_in, const int* in_sizes, int n_in,
                              void* d_out, int out_size, void* d_ws, size_t ws_size,
                              hipStream_t stream)
{
  const float* x      = (const float*)d_in[0];
  const float* cosb   = (const float*)d_in[1];
  const float* sinb   = (const float*)d_in[2];
  const float* qkv_w  = (const float*)d_in[4];
  const float* qkv_b  = (const float*)d_in[5];
  const float* proj_w = (const float*)d_in[6];
  const float* proj_b = (const float*)d_in[7];
  const float* ln1_w  = (const float*)d_in[8];
  const float* ln1_b  = (const float*)d_in[9];
  const float* ln2_w  = (const float*)d_in[10];
  const float* ln2_b  = (const float*)d_in[11];
  const float* fc1_w  = (const float*)d_in[12];
  const float* fc1_b  = (const float*)d_in[13];
  const float* fc2_w  = (const float*)d_in[14];
  const float* fc2_b  = (const float*)d_in[15];

  char* ws = (char*)d_ws;
  uint16_t* Wqkv  = (uint16_t*)(ws + 0);          // [3456][1152] bf16 = 7,962,624 B
  uint16_t* Wproj = (uint16_t*)(ws + 7962624);    // [1152][1152] bf16 = 2,654,208 B
  uint16_t* Wfc1  = (uint16_t*)(ws + 10616832);   // [4352][1152] bf16 = 10,027,008 B
  uint16_t* Wfc2  = (uint16_t*)(ws + 20643840);   // [1152][4352] bf16 = 10,027,008 B
  uint16_t* Hbuf  = (uint16_t*)(ws + 30670848);   // [16384][1152] bf16 = 37,748,736 B (LN out / attn out)
  uint16_t* QKV   = (uint16_t*)(ws + 68419584);   // [16384][3456] bf16 = 113,246,208 B
  uint16_t* MB    = QKV;                          // [16384][4352] bf16 overlays QKV (142,606,336 B)
  float* X1 = (float*)d_out;                      // fp32 [16384][1152], residual stream

  // weight transpose+cast (Bt layout [N][K], zero-padded)
  transpose_cast<<<dim3(108,36), 256, 0, stream>>>(qkv_w, Wqkv, 1152, 3456, 1152);
  transpose_cast<<<dim3(36,36),  256, 0, stream>>>(proj_w, Wproj, 1152, 1152, 1152);
  transpose_cast<<<dim3(136,36), 256, 0, stream>>>(fc1_w, Wfc1, 1152, 4304, 1152);
  transpose_cast<<<dim3(36,136), 256, 0, stream>>>(fc2_w, Wfc2, 4304, 1152, 4352);

  // LN1 -> Hbuf (bf16)
  ln_kernel<<<4096, 256, 0, stream>>>(x, ln1_w, ln1_b, Hbuf);
  // QKV = Hbuf @ Wqkv^T + b -> bf16
  gemm_bt<0><<<dim3(27,128), 256, 0, stream>>>(Hbuf, Wqkv, qkv_b, QKVN, nullptr, QKV, QKVN, HID);
  // RoPE in place on q,k
  rope_kernel<<<36864, 256, 0, stream>>>(QKV, cosb, sinb);
  // windowed attention -> Hbuf (bf16)
  attn_kernel<<<4096, 256, 0, stream>>>(QKV, Hbuf);
  // X1 = x + Hbuf @ Wproj^T + b  (fp32, into d_out)
  gemm_bt<2><<<dim3(9,128), 256, 0, stream>>>(Hbuf, Wproj, proj_b, HID, x, X1, HID, HID);
  // LN2 -> Hbuf (bf16)
  ln_kernel<<<4096, 256, 0, stream>>>(X1, ln2_w, ln2_b, Hbuf);
  // MB = gelu(Hbuf @ Wfc1^T + b)  (bf16, padded N=4352)
  gemm_bt<1><<<dim3(34,128), 256, 0, stream>>>(Hbuf, Wfc1, fc1_b, INTER, nullptr, MB, INTERP, HID);
  // out = X1 + MB @ Wfc2^T + b   (fp32, in-place on d_out)
  gemm_bt<2><<<dim3(9,128), 256, 0, stream>>>(MB, Wfc2, fc2_b, HID, X1, X1, HID, INTERP);
}

// Round 2
// 1180.013 us; speedup vs baseline: 1.1290x; 1.1290x over previous
//
#include <hip/hip_runtime.h>
#include <stdint.h>

// VisionBlock: LN1 -> QKV GEMM -> RoPE -> windowed attn (W=64) -> proj+res -> LN2 -> GELU MLP + res
// bf16 MFMA 16x16x32, fp32 accumulate. 128x128 tile, BK=64, global_load_lds width=16,
// XOR bank-conflict swizzle, XCD-grouped tile assignment.

#define SEQ   16384
#define HID   1152
#define NH    16
#define HDIM  72
#define INTER 4304
#define INTERP 4352
#define QKVN  3456

using bf16x8 = __attribute__((ext_vector_type(8))) __bf16;
using f32x4  = __attribute__((ext_vector_type(4))) float;

__device__ __forceinline__ float bf2f(uint16_t u){ return __uint_as_float(((uint32_t)u)<<16); }
__device__ __forceinline__ uint16_t f2bf(float f){
  uint32_t u = __float_as_uint(f);
  u += 0x7fffu + ((u>>16)&1u);
  return (uint16_t)(u>>16);
}
__device__ __forceinline__ float gelu_tanh(float x){
  float t = tanhf(0.7978845608028654f*(x + 0.044715f*x*x*x));
  return 0.5f*x*(1.0f + t);
}
__device__ __forceinline__ void async_load16(const void* g, void* l){
  __builtin_amdgcn_global_load_lds((__attribute__((address_space(1))) void*)(void*)g,
                                   (__attribute__((address_space(3))) void*)l, 16, 0, 0);
}

// ---------------- transpose + cast fp32[R][C] -> bf16[Cp][Rp], zero-padded ----------------
__global__ void transpose_cast(const float* __restrict__ src, uint16_t* __restrict__ dst,
                               int R, int C, int Rp)
{
  __shared__ float tile[32][33];
  const int tx = threadIdx.x & 31, ty = threadIdx.x >> 5;
  const int c = blockIdx.x*32 + tx;
  #pragma unroll
  for (int s = 0; s < 4; ++s){
    const int r = blockIdx.y*32 + ty + s*8;
    tile[ty + s*8][tx] = (r < R && c < C) ? src[(size_t)r*C + c] : 0.0f;
  }
  __syncthreads();
  #pragma unroll
  for (int s = 0; s < 4; ++s){
    const int oc = blockIdx.x*32 + ty + s*8;     // output row  (N dim)
    const int orr = blockIdx.y*32 + tx;          // output col  (K dim)
    dst[(size_t)oc*Rp + orr] = f2bf(tile[tx][ty + s*8]);
  }
}

// ---------------- LayerNorm: fp32 in -> bf16 out, one wave per row ----------------
__global__ void ln_kernel(const float* __restrict__ x, const float* __restrict__ w,
                          const float* __restrict__ b, uint16_t* __restrict__ out)
{
  const int wid = threadIdx.x >> 6, lane = threadIdx.x & 63;
  const int row = blockIdx.x*4 + wid;
  const float* xr = x + (size_t)row*HID;
  float v[18];
  float s = 0.f;
  #pragma unroll
  for (int t = 0; t < 18; ++t){ v[t] = xr[lane + t*64]; s += v[t]; }
  #pragma unroll
  for (int m = 32; m; m >>= 1) s += __shfl_xor(s, m, 64);
  const float mean = s * (1.0f/HID);
  float q = 0.f;
  #pragma unroll
  for (int t = 0; t < 18; ++t){ float d = v[t]-mean; q += d*d; }
  #pragma unroll
  for (int m = 32; m; m >>= 1) q += __shfl_xor(q, m, 64);
  const float rstd = rsqrtf(q*(1.0f/HID) + 1e-6f);
  uint16_t* orow = out + (size_t)row*HID;
  #pragma unroll
  for (int t = 0; t < 18; ++t){
    const int j = lane + t*64;
    orow[j] = f2bf((v[t]-mean)*rstd*w[j] + b[j]);
  }
}

// ---------------- RoPE in-place on bf16 qkv [SEQ][3456] (q,k only) ----------------
__global__ void rope_kernel(uint16_t* __restrict__ qkv, const float* __restrict__ cosb,
                            const float* __restrict__ sinb)
{
  const int idx = blockIdx.x*256 + threadIdx.x;      // SEQ*NH*36 threads exactly
  const int s  = idx / (NH*36);
  const int r1 = idx - s*(NH*36);
  const int h  = r1 / 36;
  const int d  = r1 - h*36;
  const float c  = cosb[s*HDIM + d];
  const float sn = sinb[s*HDIM + d];
  const size_t b = (size_t)s*QKVN + h*HDIM + d;
  float q1 = bf2f(qkv[b]), q2 = bf2f(qkv[b+36]);
  qkv[b]    = f2bf(q1*c - q2*sn);
  qkv[b+36] = f2bf(q2*c + q1*sn);
  float k1 = bf2f(qkv[b+HID]), k2 = bf2f(qkv[b+HID+36]);
  qkv[b+HID]    = f2bf(k1*c - k2*sn);
  qkv[b+HID+36] = f2bf(k2*c + k1*sn);
}

// ---------------- windowed attention: one block per (window, head) ----------------
__global__ __launch_bounds__(256,2) void attn_kernel(const uint16_t* __restrict__ qkv,
                                                     uint16_t* __restrict__ outb)
{
  __shared__ float Q[64*76];
  __shared__ float K[64*76];
  __shared__ float V[64*76];
  __shared__ float P[64*68];
  const int tid = threadIdx.x;
  const int win = blockIdx.x >> 4, h = blockIdx.x & 15;
  const size_t base = (size_t)win*64*QKVN + h*HDIM;
  {
    const int r = tid >> 2, q4 = tid & 3;
    const size_t rb = base + (size_t)r*QKVN;
    #pragma unroll
    for (int p0 = 0; p0 < 9; ++p0){
      const int p = q4*9 + p0;
      const uint32_t uq = *(const uint32_t*)(qkv + rb + 2*p);
      const uint32_t uk = *(const uint32_t*)(qkv + rb + HID + 2*p);
      const uint32_t uv = *(const uint32_t*)(qkv + rb + 2*HID + 2*p);
      Q[r*76+2*p] = bf2f((uint16_t)uq); Q[r*76+2*p+1] = bf2f((uint16_t)(uq>>16));
      K[r*76+2*p] = bf2f((uint16_t)uk); K[r*76+2*p+1] = bf2f((uint16_t)(uk>>16));
      V[r*76+2*p] = bf2f((uint16_t)uv); V[r*76+2*p+1] = bf2f((uint16_t)(uv>>16));
    }
  }
  __syncthreads();
  const int rg = tid >> 4, cg = tid & 15;
  const int r0 = rg*4, c0 = cg*4;
  float sc[4][4] = {};
  #pragma unroll 3
  for (int kk = 0; kk < 18; ++kk){
    float4 qv[4], kv[4];
    #pragma unroll
    for (int i = 0; i < 4; ++i) qv[i] = *(const float4*)&Q[(r0+i)*76 + kk*4];
    #pragma unroll
    for (int j = 0; j < 4; ++j) kv[j] = *(const float4*)&K[(c0+j)*76 + kk*4];
    #pragma unroll
    for (int i = 0; i < 4; ++i)
      #pragma unroll
      for (int j = 0; j < 4; ++j)
        sc[i][j] += qv[i].x*kv[j].x + qv[i].y*kv[j].y + qv[i].z*kv[j].z + qv[i].w*kv[j].w;
  }
  const float scale = 0.11785113019775793f;   // 72^-0.5
  #pragma unroll
  for (int i = 0; i < 4; ++i){
    float a0 = sc[i][0]*scale, a1 = sc[i][1]*scale, a2 = sc[i][2]*scale, a3 = sc[i][3]*scale;
    float m = fmaxf(fmaxf(a0,a1), fmaxf(a2,a3));
    m = fmaxf(m, __shfl_xor(m, 1, 16));
    m = fmaxf(m, __shfl_xor(m, 2, 16));
    m = fmaxf(m, __shfl_xor(m, 4, 16));
    m = fmaxf(m, __shfl_xor(m, 8, 16));
    float e0 = __expf(a0-m), e1 = __expf(a1-m), e2 = __expf(a2-m), e3 = __expf(a3-m);
    float sm = e0+e1+e2+e3;
    sm += __shfl_xor(sm, 1, 16);
    sm += __shfl_xor(sm, 2, 16);
    sm += __shfl_xor(sm, 4, 16);
    sm += __shfl_xor(sm, 8, 16);
    const float inv = 1.0f/sm;
    *(float4*)&P[(r0+i)*68 + c0] = make_float4(e0*inv, e1*inv, e2*inv, e3*inv);
  }
  __syncthreads();
  for (int d4 = cg; d4 < 18; d4 += 16){
    float4 o[4] = {};
    #pragma unroll 4
    for (int k4 = 0; k4 < 16; ++k4){
      float4 pr[4];
      #pragma unroll
      for (int i = 0; i < 4; ++i) pr[i] = *(const float4*)&P[(r0+i)*68 + k4*4];
      const float4 v0 = *(const float4*)&V[(k4*4+0)*76 + d4*4];
      const float4 v1 = *(const float4*)&V[(k4*4+1)*76 + d4*4];
      const float4 v2 = *(const float4*)&V[(k4*4+2)*76 + d4*4];
      const float4 v3 = *(const float4*)&V[(k4*4+3)*76 + d4*4];
      #pragma unroll
      for (int i = 0; i < 4; ++i){
        o[i].x += pr[i].x*v0.x + pr[i].y*v1.x + pr[i].z*v2.x + pr[i].w*v3.x;
        o[i].y += pr[i].x*v0.y + pr[i].y*v1.y + pr[i].z*v2.y + pr[i].w*v3.y;
        o[i].z += pr[i].x*v0.z + pr[i].y*v1.z + pr[i].z*v2.z + pr[i].w*v3.z;
        o[i].w += pr[i].x*v0.w + pr[i].y*v1.w + pr[i].z*v2.w + pr[i].w*v3.w;
      }
    }
    #pragma unroll
    for (int i = 0; i < 4; ++i){
      const int token = win*64 + r0 + i;
      const size_t ob = (size_t)token*HID + h*HDIM + d4*4;
      outb[ob+0] = f2bf(o[i].x); outb[ob+1] = f2bf(o[i].y);
      outb[ob+2] = f2bf(o[i].z); outb[ob+3] = f2bf(o[i].w);
    }
  }
}

// ---------------- bf16 GEMM: C[M][N] = A[M][K] @ Bt[N][K]^T ----------------
// 128x128 tile, BK=64, 1D grid (size NB*MB, multiple of 8), XCD-grouped tiles.
// LDS layout: 16 chunks per matrix; chunk c = (rowchunk rc = c>>1, k-half h = c&1),
// holds rows rc*16..+15 x 32 K-cols, with XOR swizzle: physical 8-elem slot k holds
// logical chunk k ^ ((row>>1)&3)  (makes every 8 consecutive lanes of ds_read_b128
// hit 8 disjoint bank-quads -> conflict-free).
// EPI: 0 = bf16(bias), 1 = bf16(gelu(bias)), 2 = f32(bias + residual)
template<int EPI>
__global__ __launch_bounds__(256,3) void gemm_bt(
    const uint16_t* __restrict__ A, const uint16_t* __restrict__ Bt,
    const float* __restrict__ bias, int Nb,
    const float* res, void* outp, int N, int K, int NB)
{
  __shared__ uint16_t sA[128*64];
  __shared__ uint16_t sB[128*64];
  const int tid = threadIdx.x, wid = tid >> 6, lane = tid & 63;
  // XCD-grouped tile id: HW dispatches blockIdx round-robin over 8 XCDs;
  // give each XCD a contiguous run of m-strip-major tiles so A-strip sharers
  // (NB consecutive tiles) land in one XCD's L2.
  const int per  = gridDim.x >> 3;
  const int tile = (blockIdx.x & 7)*per + (blockIdx.x >> 3);
  const int mb   = tile / NB;
  const int mBase = mb*128, nBase = (tile - mb*NB)*128;
  const int wm = wid >> 1, wn = wid & 1;
  // staging lane mapping (lane l -> row sr, physical slot sk; fetch logical chunk gk)
  const int sr = lane >> 2;
  const int sk = lane & 3;
  const int gk = sk ^ ((sr >> 1) & 3);
  // fragment read mapping (row rr, logical k-quad rq lives at physical slot rp)
  const int rr = lane & 15;
  const int rq = lane >> 4;
  const int rp = rq ^ ((rr >> 1) & 3);
  f32x4 acc[4][4] = {};

  for (int k0 = 0; k0 < K; k0 += 64){
    __syncthreads();
    #pragma unroll
    for (int j = 0; j < 4; ++j){
      const int c  = wid*4 + j;
      const int rc = c >> 1, h = c & 1;
      const size_t gcol = (size_t)(k0 + h*32 + gk*8);
      async_load16(A  + (size_t)(mBase + rc*16 + sr)*K + gcol, &sA[c*512]);
      async_load16(Bt + (size_t)(nBase + rc*16 + sr)*K + gcol, &sB[c*512]);
    }
    __syncthreads();
    #pragma unroll
    for (int h = 0; h < 2; ++h){
      bf16x8 af[4], bfr[4];
      #pragma unroll
      for (int i = 0; i < 4; ++i)
        af[i] = *(const bf16x8*)&sA[((wm*4 + i)*2 + h)*512 + rr*32 + rp*8];
      #pragma unroll
      for (int j = 0; j < 4; ++j)
        bfr[j] = *(const bf16x8*)&sB[((wn*4 + j)*2 + h)*512 + rr*32 + rp*8];
      #pragma unroll
      for (int i = 0; i < 4; ++i)
        #pragma unroll
        for (int j = 0; j < 4; ++j)
          acc[i][j] = __builtin_amdgcn_mfma_f32_16x16x32_bf16(af[i], bfr[j], acc[i][j], 0, 0, 0);
    }
  }

  const int rqd = (lane>>4)*4, cl = lane & 15;
  #pragma unroll
  for (int i = 0; i < 4; ++i){
    #pragma unroll
    for (int j = 0; j < 4; ++j){
      const int col = nBase + wn*64 + j*16 + cl;
      const float bv = (col < Nb) ? bias[col] : 0.0f;
      #pragma unroll
      for (int r = 0; r < 4; ++r){
        const int row = mBase + wm*64 + i*16 + rqd + r;
        const float v = acc[i][j][r] + bv;
        const size_t o = (size_t)row*N + col;
        if (EPI == 0)      ((uint16_t*)outp)[o] = f2bf(v);
        else if (EPI == 1) ((uint16_t*)outp)[o] = f2bf(gelu_tanh(v));
        else               ((float*)outp)[o] = v + res[o];
      }
    }
  }
}

// ---------------- host launcher ----------------
extern "C" void kernel_launch(void* const* d_in, const int* in_sizes, int n_in,
                              void* d_out, int out_size, void* d_ws, size_t ws_size,
                              hipStream_t stream)
{
  const float* x      = (const float*)d_in[0];
  const float* cosb   = (const float*)d_in[1];
  const float* sinb   = (const float*)d_in[2];
  const float* qkv_w  = (const float*)d_in[4];
  const float* qkv_b  = (const float*)d_in[5];
  const float* proj_w = (const float*)d_in[6];
  const float* proj_b = (const float*)d_in[7];
  const float* ln1_w  = (const float*)d_in[8];
  const float* ln1_b  = (const float*)d_in[9];
  const float* ln2_w  = (const float*)d_in[10];
  const float* ln2_b  = (const float*)d_in[11];
  const float* fc1_w  = (const float*)d_in[12];
  const float* fc1_b  = (const float*)d_in[13];
  const float* fc2_w  = (const float*)d_in[14];
  const float* fc2_b  = (const float*)d_in[15];

  char* ws = (char*)d_ws;
  uint16_t* Wqkv  = (uint16_t*)(ws + 0);          // [3456][1152] bf16
  uint16_t* Wproj = (uint16_t*)(ws + 7962624);    // [1152][1152] bf16
  uint16_t* Wfc1  = (uint16_t*)(ws + 10616832);   // [4352][1152] bf16
  uint16_t* Wfc2  = (uint16_t*)(ws + 20643840);   // [1152][4352] bf16
  uint16_t* Hbuf  = (uint16_t*)(ws + 30670848);   // [16384][1152] bf16 (LN out / attn out)
  uint16_t* QKV   = (uint16_t*)(ws + 68419584);   // [16384][3456] bf16
  uint16_t* MB    = QKV;                          // [16384][4352] bf16 overlays QKV
  float* X1 = (float*)d_out;                      // fp32 [16384][1152], residual stream

  // weight transpose+cast (Bt layout [N][K], zero-padded)
  transpose_cast<<<dim3(108,36), 256, 0, stream>>>(qkv_w, Wqkv, 1152, 3456, 1152);
  transpose_cast<<<dim3(36,36),  256, 0, stream>>>(proj_w, Wproj, 1152, 1152, 1152);
  transpose_cast<<<dim3(136,36), 256, 0, stream>>>(fc1_w, Wfc1, 1152, 4304, 1152);
  transpose_cast<<<dim3(36,136), 256, 0, stream>>>(fc2_w, Wfc2, 4304, 1152, 4352);

  // LN1 -> Hbuf (bf16)
  ln_kernel<<<4096, 256, 0, stream>>>(x, ln1_w, ln1_b, Hbuf);
  // QKV = Hbuf @ Wqkv^T + b -> bf16
  gemm_bt<0><<<27*128, 256, 0, stream>>>(Hbuf, Wqkv, qkv_b, QKVN, nullptr, QKV, QKVN, HID, 27);
  // RoPE in place on q,k
  rope_kernel<<<36864, 256, 0, stream>>>(QKV, cosb, sinb);
  // windowed attention -> Hbuf (bf16)
  attn_kernel<<<4096, 256, 0, stream>>>(QKV, Hbuf);
  // X1 = x + Hbuf @ Wproj^T + b  (fp32, into d_out)
  gemm_bt<2><<<9*128, 256, 0, stream>>>(Hbuf, Wproj, proj_b, HID, x, X1, HID, HID, 9);
  // LN2 -> Hbuf (bf16)
  ln_kernel<<<4096, 256, 0, stream>>>(X1, ln2_w, ln2_b, Hbuf);
  // MB = gelu(Hbuf @ Wfc1^T + b)  (bf16, padded N=4352)
  gemm_bt<1><<<34*128, 256, 0, stream>>>(Hbuf, Wfc1, fc1_b, INTER, nullptr, MB, INTERP, HID, 34);
  // out = X1 + MB @ Wfc2^T + b   (fp32, in-place on d_out)
  gemm_bt<2><<<9*128, 256, 0, stream>>>(MB, Wfc2, fc2_b, HID, X1, X1, HID, INTERP, 9);
}